// Round 1
// baseline (1745.102 us; speedup 1.0000x reference)
//
#include <hip/hip_runtime.h>
#include <math.h>

#define EPSF 1e-15f

// ---------------------------------------------------------------------------
// prep: transpose W1 [64][320] -> W1t [320][64], W2/W3 [64][64] -> [64][64]^T
// so that inner-loop weight reads are contiguous + wave-uniform (s_load).
// ---------------------------------------------------------------------------
__global__ void prep_kernel(const float* __restrict__ W1,
                            const float* __restrict__ W2,
                            const float* __restrict__ W3,
                            float* __restrict__ W1t,
                            float* __restrict__ W2t,
                            float* __restrict__ W3t) {
    int idx = blockIdx.x * blockDim.x + threadIdx.x;
    if (idx < 320 * 64) {
        int k = idx >> 6, j = idx & 63;
        W1t[idx] = W1[j * 320 + k];
    } else if (idx < 320 * 64 + 4096) {
        int r = idx - 320 * 64;
        int k = r >> 6, j = r & 63;
        W2t[r] = W2[j * 64 + k];
    } else if (idx < 320 * 64 + 8192) {
        int r = idx - 320 * 64 - 4096;
        int k = r >> 6, j = r & 63;
        W3t[r] = W3[j * 64 + k];
    }
}

// ---------------------------------------------------------------------------
// one mobius-linear "stage" applied to v (in registers):
//   h  = expmap0(v);  x = projx(relu(h));  t = logmap0(x);  v = t @ Wt + b
// ---------------------------------------------------------------------------
__device__ __forceinline__ void mlp_stage(float (&v)[64],
                                          const float* __restrict__ Wt,
                                          const float* __restrict__ b,
                                          float sc, float maxn) {
    float n2 = 0.f;
#pragma unroll
    for (int j = 0; j < 64; ++j) n2 = fmaf(v[j], v[j], n2);
    float n  = sqrtf(n2);
    float he = tanhf(sc * n) / (n * sc + EPSF);   // expmap0 elementwise factor

    float t[64];
    float rn2 = 0.f;
#pragma unroll
    for (int j = 0; j < 64; ++j) {
        float h = fmaxf(he * v[j], 0.f);          // relu
        t[j] = h;
        rn2 = fmaf(h, h, rn2);
    }
    float rn = sqrtf(rn2);
    float ps = fminf(maxn / fmaxf(rn, EPSF), 1.0f);   // projx scale
    float pn = rn * ps;                                // norm after projx
    float g  = atanhf(fminf(sc * pn, 1.0f - 1e-5f)) / (sc * (pn + EPSF));
    float f  = ps * g;                                 // combined factor on t

#pragma unroll
    for (int j = 0; j < 64; ++j) v[j] = b[j];
#pragma unroll
    for (int k = 0; k < 64; ++k) {
        float tk = f * t[k];
        const float* w = Wt + k * 64;
#pragma unroll
        for (int j = 0; j < 64; ++j) v[j] = fmaf(tk, w[j], v[j]);
    }
}

// ---------------------------------------------------------------------------
// edge kernel: one thread per edge, everything in registers.
// ---------------------------------------------------------------------------
__global__ void __launch_bounds__(256)
edge_kernel(const float* __restrict__ hV, const float* __restrict__ hE,
            const int* __restrict__ src, const int* __restrict__ dst,
            const float* __restrict__ logc,
            const float* __restrict__ W1t, const float* __restrict__ b1,
            const float* __restrict__ W2t, const float* __restrict__ b2,
            const float* __restrict__ W3t, const float* __restrict__ b3,
            float* __restrict__ sums, float* __restrict__ counts,
            int n_edges) {
    int e = blockIdx.x * blockDim.x + threadIdx.x;
    if (e >= n_edges) return;

    float c    = expf(logc[0]);
    float sc   = sqrtf(c);
    float maxn = (1.0f - 1e-5f) / sc;

    int s = src[e], d = dst[e];
    const float4* hE4 = reinterpret_cast<const float4*>(hE) + (size_t)e * 48;
    const float4* hVs = reinterpret_cast<const float4*>(hV) + (size_t)s * 16;
    const float4* hVd = reinterpret_cast<const float4*>(hV) + (size_t)d * 16;

    // projx scales for the two gathered node rows (rows are L2-hot, re-read below)
    float ssqS = 0.f, ssqD = 0.f;
#pragma unroll
    for (int q = 0; q < 16; ++q) {
        float4 a = hVs[q];
        ssqS += a.x * a.x + a.y * a.y + a.z * a.z + a.w * a.w;
        float4 bb = hVd[q];
        ssqD += bb.x * bb.x + bb.y * bb.y + bb.z * bb.z + bb.w * bb.w;
    }
    float sS = fminf(maxn / fmaxf(sqrtf(ssqS), EPSF), 1.0f);
    float sD = fminf(maxn / fmaxf(sqrtf(ssqD), EPSF), 1.0f);

    // GEMM1: out1 = logmap0(projx-concat) @ W1^T + b1, with scales deferred:
    //   AE accumulates raw h_E dots (scale sE*g applied later),
    //   AV accumulates (already projx-scaled) node dots (scale g later).
    float AE[64], AV[64];
#pragma unroll
    for (int j = 0; j < 64; ++j) { AE[j] = 0.f; AV[j] = 0.f; }

    float ssqE = 0.f, ssqV = 0.f;

    for (int q = 0; q < 48; ++q) {           // h_E segment, k in [0,192)
        float4 x = hE4[q];
        ssqE += x.x * x.x + x.y * x.y + x.z * x.z + x.w * x.w;
        const float* w = W1t + q * 4 * 64;
#pragma unroll
        for (int j = 0; j < 64; ++j) {
            float a = AE[j];
            a = fmaf(x.x, w[j], a);
            a = fmaf(x.y, w[64 + j], a);
            a = fmaf(x.z, w[128 + j], a);
            a = fmaf(x.w, w[192 + j], a);
            AE[j] = a;
        }
    }
    for (int q = 0; q < 16; ++q) {           // src segment, k in [192,256)
        float4 x = hVs[q];
        x.x *= sS; x.y *= sS; x.z *= sS; x.w *= sS;
        ssqV += x.x * x.x + x.y * x.y + x.z * x.z + x.w * x.w;
        const float* w = W1t + (192 + q * 4) * 64;
#pragma unroll
        for (int j = 0; j < 64; ++j) {
            float a = AV[j];
            a = fmaf(x.x, w[j], a);
            a = fmaf(x.y, w[64 + j], a);
            a = fmaf(x.z, w[128 + j], a);
            a = fmaf(x.w, w[192 + j], a);
            AV[j] = a;
        }
    }
    for (int q = 0; q < 16; ++q) {           // dst segment, k in [256,320)
        float4 x = hVd[q];
        x.x *= sD; x.y *= sD; x.z *= sD; x.w *= sD;
        ssqV += x.x * x.x + x.y * x.y + x.z * x.z + x.w * x.w;
        const float* w = W1t + (256 + q * 4) * 64;
#pragma unroll
        for (int j = 0; j < 64; ++j) {
            float a = AV[j];
            a = fmaf(x.x, w[j], a);
            a = fmaf(x.y, w[64 + j], a);
            a = fmaf(x.z, w[128 + j], a);
            a = fmaf(x.w, w[192 + j], a);
            AV[j] = a;
        }
    }

    float sE = fminf(maxn / fmaxf(sqrtf(ssqE), EPSF), 1.0f);
    float nt = sqrtf(sE * sE * ssqE + ssqV);           // norm of projected concat
    float g  = atanhf(fminf(sc * nt, 1.0f - 1e-5f)) / (sc * (nt + EPSF));
    float gE = g * sE;

    float v[64];
#pragma unroll
    for (int j = 0; j < 64; ++j) v[j] = fmaf(gE, AE[j], fmaf(g, AV[j], b1[j]));

    mlp_stage(v, W2t, b2, sc, maxn);   // layer 2
    mlp_stage(v, W3t, b3, sc, maxn);   // layer 3 -> v = z3 (pre-expmap of h_msg)

    // tangent = logmap0(expmap0(v)) computed faithfully (incl. clamps/EPS)
    float n2 = 0.f;
#pragma unroll
    for (int j = 0; j < 64; ++j) n2 = fmaf(v[j], v[j], n2);
    float n  = sqrtf(n2);
    float he = tanhf(sc * n) / (n * sc + EPSF);
    float hn = he * n;                                   // ||expmap0(v)||
    float g3 = atanhf(fminf(sc * hn, 1.0f - 1e-5f)) / (sc * (hn + EPSF));
    float f3 = g3 * he;

    float* srow = sums + (size_t)s * 64;
#pragma unroll
    for (int j = 0; j < 64; ++j) atomicAdd(&srow[j], f3 * v[j]);
    atomicAdd(&counts[s], 1.0f);
}

// ---------------------------------------------------------------------------
// node kernel: agg = expmap0(sums/max(cnt,1)); out = projx(mobius_add(projx(hV), agg))
// ---------------------------------------------------------------------------
__global__ void __launch_bounds__(256)
node_kernel(const float* __restrict__ hV, const float* __restrict__ logc,
            const float* __restrict__ sums, const float* __restrict__ counts,
            float* __restrict__ out, int n_nodes) {
    int nd = blockIdx.x * blockDim.x + threadIdx.x;
    if (nd >= n_nodes) return;

    float c    = expf(logc[0]);
    float sc   = sqrtf(c);
    float maxn = (1.0f - 1e-5f) / sc;

    float inv = 1.0f / fmaxf(counts[nd], 1.0f);

    float at[64];
    float an2 = 0.f;
    const float4* sr = reinterpret_cast<const float4*>(sums) + (size_t)nd * 16;
#pragma unroll
    for (int q = 0; q < 16; ++q) {
        float4 a = sr[q];
        a.x *= inv; a.y *= inv; a.z *= inv; a.w *= inv;
        at[q * 4 + 0] = a.x; at[q * 4 + 1] = a.y;
        at[q * 4 + 2] = a.z; at[q * 4 + 3] = a.w;
        an2 += a.x * a.x + a.y * a.y + a.z * a.z + a.w * a.w;
    }
    float an = sqrtf(an2);
    float ae = tanhf(sc * an) / (an * sc + EPSF);   // y = ae * at  (agg)

    // x = projx(hV row)
    float xv[64];
    float hs2 = 0.f;
    const float4* hr = reinterpret_cast<const float4*>(hV) + (size_t)nd * 16;
#pragma unroll
    for (int q = 0; q < 16; ++q) {
        float4 a = hr[q];
        xv[q * 4 + 0] = a.x; xv[q * 4 + 1] = a.y;
        xv[q * 4 + 2] = a.z; xv[q * 4 + 3] = a.w;
        hs2 += a.x * a.x + a.y * a.y + a.z * a.z + a.w * a.w;
    }
    float sX = fminf(maxn / fmaxf(sqrtf(hs2), EPSF), 1.0f);

    float x2 = 0.f, y2 = 0.f, xy = 0.f;
#pragma unroll
    for (int j = 0; j < 64; ++j) {
        float x = sX * xv[j];
        float y = ae * at[j];
        xv[j] = x; at[j] = y;
        x2 = fmaf(x, x, x2);
        y2 = fmaf(y, y, y2);
        xy = fmaf(x, y, xy);
    }

    float ca  = 1.f + 2.f * c * xy + c * y2;
    float cb  = 1.f - c * x2;
    float den = 1.f + 2.f * c * xy + c * c * x2 * y2 + EPSF;
    float id  = 1.f / den;

    float res[64];
    float rn2 = 0.f;
#pragma unroll
    for (int j = 0; j < 64; ++j) {
        float r = (ca * xv[j] + cb * at[j]) * id;
        res[j] = r;
        rn2 = fmaf(r, r, rn2);
    }
    float rs = fminf(maxn / fmaxf(sqrtf(rn2), EPSF), 1.0f);

    float4* orow = reinterpret_cast<float4*>(out) + (size_t)nd * 16;
#pragma unroll
    for (int q = 0; q < 16; ++q) {
        float4 o;
        o.x = rs * res[q * 4 + 0];
        o.y = rs * res[q * 4 + 1];
        o.z = rs * res[q * 4 + 2];
        o.w = rs * res[q * 4 + 3];
        orow[q] = o;
    }
}

// ---------------------------------------------------------------------------
extern "C" void kernel_launch(void* const* d_in, const int* in_sizes, int n_in,
                              void* d_out, int out_size, void* d_ws, size_t ws_size,
                              hipStream_t stream) {
    const float* hV   = (const float*)d_in[0];
    const float* hE   = (const float*)d_in[1];
    const int*   src  = (const int*)d_in[2];
    const int*   dst  = (const int*)d_in[3];
    const float* logc = (const float*)d_in[4];
    const float* W1   = (const float*)d_in[5];
    const float* b1   = (const float*)d_in[6];
    const float* W2   = (const float*)d_in[7];
    const float* b2   = (const float*)d_in[8];
    const float* W3   = (const float*)d_in[9];
    const float* b3   = (const float*)d_in[10];

    int n_nodes = in_sizes[0] / 64;
    int n_edges = in_sizes[2];
    float* out = (float*)d_out;

    float* ws     = (float*)d_ws;
    float* sums   = ws;                                  // n_nodes*64
    float* counts = sums + (size_t)n_nodes * 64;         // n_nodes
    float* W1t    = counts + n_nodes;                    // 320*64
    float* W2t    = W1t + 320 * 64;                      // 64*64
    float* W3t    = W2t + 64 * 64;                       // 64*64

    hipMemsetAsync(sums, 0, ((size_t)n_nodes * 64 + n_nodes) * sizeof(float), stream);

    prep_kernel<<<(320 * 64 + 8192 + 255) / 256, 256, 0, stream>>>(W1, W2, W3, W1t, W2t, W3t);

    edge_kernel<<<(n_edges + 255) / 256, 256, 0, stream>>>(
        hV, hE, src, dst, logc, W1t, b1, W2t, b2, W3t, b3, sums, counts, n_edges);

    node_kernel<<<(n_nodes + 255) / 256, 256, 0, stream>>>(
        hV, logc, sums, counts, out, n_nodes);
}